// Round 10
// baseline (177.903 us; speedup 1.0000x reference)
//
#include <hip/hip_runtime.h>
#include <hip/hip_bf16.h>
#include <math.h>
#include <stdint.h>

// Problem: B=64, SQ=64, SD=512, H=128
#define BB 64
#define SQN 64
#define SDN 512
#define HH 128

typedef __attribute__((ext_vector_type(8))) short bf16x8;     // 8 bf16 = 4 VGPRs
typedef __attribute__((ext_vector_type(16))) float f32x16;    // 16 acc regs

__device__ __forceinline__ short f2bf(float f) {
  union { float f; unsigned u; } x; x.f = f;
  unsigned r = x.u + 0x7fffu + ((x.u >> 16) & 1u);   // RNE
  return (short)(r >> 16);
}

// ---- fused compact+convert (pad to 64-row multiples) ----
// blocks [0,2048): d-gather; each owns 32 compacted rows of one (b,side) and
// redundantly ballot-scans that bs's 512-entry mask in LDS (L2-hit, cheap).
// blocks [2048,2080): q convert; block 2048 zeroes the loss counter.
// Dropping masked rows is exact under the masked-zero argument (maxsim inits
// rmax at 0; true max over ~256 valid t is >= 0 w.p. 1-2^-256). Pad rows
// (perm=-1) convert to zero rows -> dots 0 <= max.
__global__ __launch_bounds__(256)
void convert_kernel(const float* __restrict__ q, const float* __restrict__ dp,
                    const float* __restrict__ dn,
                    const int* __restrict__ mp, const int* __restrict__ mn,
                    short* __restrict__ oq, short* __restrict__ od,
                    int* __restrict__ nchunks, int* __restrict__ counter) {
  const int tid = threadIdx.x;
  if (blockIdx.x < 2048) {
    const int gid = blockIdx.x;
    const int bs  = gid >> 4;       // side*64+b
    const int sub = gid & 15;       // which 32-row slice
    const int side = bs >> 6, b = bs & 63;
    const int* mask = side ? mn : mp;
    const float* srcmat = side ? dn : dp;
    __shared__ int perm_lds[SDN];
    __shared__ int pad_s;
    if (tid < 64) {
      int run = 0;
      #pragma unroll
      for (int it = 0; it < SDN / 64; ++it) {
        int t = it * 64 + tid;
        int m = mask[b * SDN + t];
        unsigned long long bal = __ballot(m != 0);
        int pos = run + __popcll(bal & ((1ull << tid) - 1ull));
        if (m) perm_lds[pos] = t;
        run += (int)__popcll(bal);
      }
      int pad = (run + 63) & ~63;          // 64-row quantization
      for (int j = run + tid; j < pad; j += 64) perm_lds[j] = -1;
      if (tid == 0) {
        pad_s = pad;
        if (sub == 0) nchunks[bs] = pad >> 6;
      }
    }
    __syncthreads();
    const int pad = pad_s;
    const int l32 = tid & 31;
    #pragma unroll
    for (int p = 0; p < 4; ++p) {          // 8 rows/pass x 32 lanes/row
      int j = sub * 32 + p * 8 + (tid >> 5);
      if (j < pad) {
        int src_t = perm_lds[j];
        float4 v = make_float4(0.f, 0.f, 0.f, 0.f);
        if (src_t >= 0)
          v = ((const float4*)(srcmat + ((size_t)b * SDN + src_t) * HH))[l32];
        short4 o; o.x = f2bf(v.x); o.y = f2bf(v.y); o.z = f2bf(v.z); o.w = f2bf(v.w);
        *(short4*)&od[((size_t)bs * SDN + j) * HH + l32 * 4] = o;
      }
    }
  } else {
    if (blockIdx.x == 2048 && tid == 0) counter[0] = 0;
    const int bq = blockIdx.x - 2048;      // 0..31; q has 131072 float4
    #pragma unroll
    for (int it = 0; it < 16; ++it) {
      int i = bq * 4096 + it * 256 + tid;
      float4 v = ((const float4*)q)[i];
      short4 o; o.x = f2bf(v.x); o.y = f2bf(v.y); o.z = f2bf(v.z); o.w = f2bf(v.w);
      *(short4*)&oq[i * 4] = o;
    }
  }
}

// Persistent maxsim + fused loss — LDS-FREE, BARRIER-FREE hot loop.
//
// Round 9 finding: per-chunk iteration time was ~constant (~9k cyc)
// regardless of chunk size -> the LDS double-buffer never overlapped:
// d_lds[buf]/d_lds[buf^1] are one object, so alias analysis forces
// s_waitcnt vmcnt(0) before the compute-phase ds_reads every iteration,
// and the block barrier couples all 4 waves to the slowest load.
//
// Fix: each wave streams d fragments DIRECTLY global -> VGPR (d_c is
// L1/L2-hot; kc-loop 16B reads reuse 128B lines in L1; the block's 4 waves
// share L1). Explicit unroll-by-2 ping-pong with STATIC register arrays
// dA/dB: load strip i+1 while 16 MFMAs (~512 SIMD-cyc) run on strip i.
// Plain VGPR loads -> normal compiler vmcnt(N) pipelining, no barriers.
//
// Wave = 1 query (qfrag 64 VGPRs provably resident - r8 lesson: 2 queries
// made the allocator rematerialize). Strip = 32 t-rows x full K=128.
// Per bs: strips = 2*nch64, max-accumulated in regs; finalize = 9 shuffles.
//
// Regs: qfrag 64 + dA/dB 64 + acc 32 + misc ~25 = ~185 < 256 cap (256,2).
// NEVER cap below need (r3/r4: spilled 843/217 MB scratch).
__global__ __launch_bounds__(256, 2)
void maxsim_kernel(const short* __restrict__ qb,
                   const short* __restrict__ dc,
                   const int* __restrict__ nchunks,
                   float* __restrict__ scores,
                   int* __restrict__ counter,
                   float* __restrict__ out) {
  const int aslc = blockIdx.x;   // 0..15
  const int bs0  = blockIdx.y * 4;

  __shared__ int islast_s;

  const int tid = threadIdx.x;
  const int ln  = tid & 63;
  const int w   = tid >> 6;
  const int l31 = ln & 31;
  const int kh  = ln >> 5;
  const int a   = aslc * 4 + w;  // this wave's query (owns all 64 s)

  int nstr[4];
  #pragma unroll
  for (int i = 0; i < 4; ++i) nstr[i] = nchunks[bs0 + i] * 2;  // 32-row strips

  // ---- q as B-operand (persistent): n = half*32+l31, k = kc*16 + kh*8 + j ----
  bf16x8 qfrag[2][8];
  #pragma unroll
  for (int half = 0; half < 2; ++half) {
    const short* qrow = qb + ((size_t)a * SQN + half * 32 + l31) * HH + kh * 8;
    #pragma unroll
    for (int kc = 0; kc < 8; ++kc)
      qfrag[half][kc] = *(const bf16x8*)(qrow + kc * 16);
  }

  float rmaxh[2] = {0.f, 0.f};   // masked-zero: true max >= 0

// A-operand strip load: m = strip*32 + l31 (t), k-half = kh. 16B/lane.
#define LOAD_STRIP(dst, bsi, stri) do {                                        \
    const short* p_ = dc + ((size_t)(bsi) * SDN + (stri) * 32 + l31) * HH + kh * 8; \
    _Pragma("unroll")                                                          \
    for (int kc_ = 0; kc_ < 8; ++kc_)                                          \
      dst[kc_] = *(const bf16x8*)(p_ + kc_ * 16);                              \
  } while (0)

// 16 MFMA on one strip + in-register max trees (C: col=l31=s within half;
// the 16 regs are this lane's kh-group of t's).
#define COMPUTE(dv) do {                                                       \
    f32x16 acc0 = {0,0,0,0,0,0,0,0,0,0,0,0,0,0,0,0};                           \
    f32x16 acc1 = {0,0,0,0,0,0,0,0,0,0,0,0,0,0,0,0};                           \
    _Pragma("unroll")                                                          \
    for (int kc_ = 0; kc_ < 8; ++kc_) {                                        \
      acc0 = __builtin_amdgcn_mfma_f32_32x32x16_bf16(dv[kc_], qfrag[0][kc_], acc0, 0, 0, 0); \
      acc1 = __builtin_amdgcn_mfma_f32_32x32x16_bf16(dv[kc_], qfrag[1][kc_], acc1, 0, 0, 0); \
    }                                                                          \
    float m0_ = acc0[0], m1_ = acc1[0];                                        \
    _Pragma("unroll")                                                          \
    for (int r_ = 1; r_ < 16; ++r_) {                                          \
      m0_ = fmaxf(m0_, acc0[r_]); m1_ = fmaxf(m1_, acc1[r_]);                  \
    }                                                                          \
    rmaxh[0] = fmaxf(rmaxh[0], m0_); rmaxh[1] = fmaxf(rmaxh[1], m1_);          \
  } while (0)

// bs finished: merge kh t-halves (lanes ln^32 hold same s, other t-half),
// then sum the 64 s values; lane 0 stores the score.
#define FINALIZE(bii) do {                                                     \
    float v0_ = fmaxf(rmaxh[0], __shfl_xor(rmaxh[0], 32));                     \
    float v1_ = fmaxf(rmaxh[1], __shfl_xor(rmaxh[1], 32));                     \
    float s_ = v0_ + v1_;                                                      \
    s_ += __shfl_xor(s_, 1);  s_ += __shfl_xor(s_, 2);  s_ += __shfl_xor(s_, 4); \
    s_ += __shfl_xor(s_, 8);  s_ += __shfl_xor(s_, 16);                        \
    if (ln == 0) scores[(size_t)a * (2 * BB) + bs0 + (bii)] = s_;              \
    rmaxh[0] = 0.f; rmaxh[1] = 0.f;                                            \
  } while (0)

  bf16x8 dA[8], dB[8];
  int bi = 0, st = 0;
  LOAD_STRIP(dA, bs0, 0);

  for (;;) {
    // ---- phase A: prefetch into dB, compute dA ----
    {
      int nbi = bi, nst = st + 1;
      if (nst == nstr[bi]) { nst = 0; nbi = bi + 1; }
      const bool hn = (nbi < 4);
      if (hn) LOAD_STRIP(dB, bs0 + nbi, nst);
      COMPUTE(dA);
      if (nst == 0) FINALIZE(bi);
      if (!hn) break;
      bi = nbi; st = nst;
    }
    // ---- phase B: prefetch into dA, compute dB ----
    {
      int nbi = bi, nst = st + 1;
      if (nst == nstr[bi]) { nst = 0; nbi = bi + 1; }
      const bool hn = (nbi < 4);
      if (hn) LOAD_STRIP(dA, bs0 + nbi, nst);
      COMPUTE(dB);
      if (nst == 0) FINALIZE(bi);
      if (!hn) break;
      bi = nbi; st = nst;
    }
  }

#undef LOAD_STRIP
#undef COMPUTE
#undef FINALIZE

  // ---- fused loss: 512th block to finish computes it ----
  __syncthreads();                 // all waves' score stores issued+drained
  if (tid == 0) {
    __threadfence();               // release: our scores visible device-wide
    int old = atomicAdd(counter, 1);
    islast_s = (old == 511);
  }
  __syncthreads();
  if (!islast_s) return;
  __threadfence();                 // acquire: see all blocks' scores

  // loss = mean_a [ logsumexp(scores[a,:]) - scores[a,a] ]; 4 waves x 16 rows
  __shared__ float part[4];
  float acc = 0.f;
  for (int i = 0; i < 16; ++i) {
    int r = w * 16 + i;
    float v0 = scores[r * 128 + ln];
    float v1 = scores[r * 128 + 64 + ln];
    float mx = fmaxf(v0, v1);
    #pragma unroll
    for (int off = 32; off >= 1; off >>= 1) mx = fmaxf(mx, __shfl_xor(mx, off));
    float e = __expf(v0 - mx) + __expf(v1 - mx);
    #pragma unroll
    for (int off = 32; off >= 1; off >>= 1) e += __shfl_xor(e, off);
    float lse = mx + __logf(e);
    float diag = __shfl(v0, r);    // r < 64: diagonal lives in v0 at lane r
    acc += lse - diag;
  }
  if (ln == 0) part[w] = acc;
  __syncthreads();
  if (tid == 0)
    out[0] = (part[0] + part[1] + part[2] + part[3]) * (1.0f / 64.0f);
}

extern "C" void kernel_launch(void* const* d_in, const int* in_sizes, int n_in,
                              void* d_out, int out_size, void* d_ws, size_t ws_size,
                              hipStream_t stream) {
  const float* q        = (const float*)d_in[0];
  const float* d_pos    = (const float*)d_in[1];
  const float* d_neg    = (const float*)d_in[2];
  const int*   mask_pos = (const int*)d_in[3];
  const int*   mask_neg = (const int*)d_in[4];

  // ws layout: q_bf 1 MB | d_c 16 MB | nchunks | scores | counter
  short* q_bf = (short*)d_ws;                                  // 524288 shorts
  short* d_c  = q_bf + (size_t)BB * SQN * HH;                  // 8388608 shorts
  int*   nchunks = (int*)(d_c + (size_t)2 * BB * SDN * HH);    // 128 ints
  float* scores  = (float*)(nchunks + 128);                    // 8192 floats
  int*   counter = (int*)(scores + BB * 2 * BB);               // 1 int

  convert_kernel<<<2080, 256, 0, stream>>>(q, d_pos, d_neg, mask_pos, mask_neg,
                                           q_bf, d_c, nchunks, counter);

  dim3 grid(16 /*a-slices*/, 32 /*bs-quads*/);
  maxsim_kernel<<<grid, 256, 0, stream>>>(q_bf, d_c, nchunks, scores,
                                          counter, (float*)d_out);
}

// Round 11
// 146.796 us; speedup vs baseline: 1.2119x; 1.2119x over previous
//
#include <hip/hip_runtime.h>
#include <hip/hip_bf16.h>
#include <math.h>
#include <stdint.h>

// Problem: B=64, SQ=64, SD=512, H=128
#define BB 64
#define SQN 64
#define SDN 512
#define HH 128

typedef __attribute__((ext_vector_type(8))) short bf16x8;     // 8 bf16 = 4 VGPRs
typedef __attribute__((ext_vector_type(16))) float f32x16;    // 16 acc regs

__device__ __forceinline__ short f2bf(float f) {
  union { float f; unsigned u; } x; x.f = f;
  unsigned r = x.u + 0x7fffu + ((x.u >> 16) & 1u);   // RNE
  return (short)(r >> 16);
}

__device__ __forceinline__ void gl_lds16(const short* g, short* l) {
  __builtin_amdgcn_global_load_lds(
      (const __attribute__((address_space(1))) unsigned int*)g,
      (__attribute__((address_space(3))) unsigned int*)l, 16, 0, 0);
}

// ---- fused compact+convert (128-row quantization, matches maxsim chunks) ----
// blocks [0,2048): d-gather; each owns 32 compacted rows of one (b,side) and
// redundantly ballot-scans that bs's 512-entry mask in LDS (L2-hit, cheap).
// blocks [2048,2080): q convert; block 2048 zeroes the loss counter.
// Dropping masked rows is exact under the masked-zero argument (maxsim inits
// rmax at 0; true max over ~256 valid t is >= 0 w.p. 1-2^-256). Pad rows
// (perm=-1) convert to zero rows -> dots 0 <= max.
__global__ __launch_bounds__(256)
void convert_kernel(const float* __restrict__ q, const float* __restrict__ dp,
                    const float* __restrict__ dn,
                    const int* __restrict__ mp, const int* __restrict__ mn,
                    short* __restrict__ oq, short* __restrict__ od,
                    int* __restrict__ nchunks, int* __restrict__ counter) {
  const int tid = threadIdx.x;
  if (blockIdx.x < 2048) {
    const int gid = blockIdx.x;
    const int bs  = gid >> 4;       // side*64+b
    const int sub = gid & 15;       // which 32-row slice
    const int side = bs >> 6, b = bs & 63;
    const int* mask = side ? mn : mp;
    const float* srcmat = side ? dn : dp;
    __shared__ int perm_lds[SDN];
    __shared__ int pad_s;
    if (tid < 64) {
      int run = 0;
      #pragma unroll
      for (int it = 0; it < SDN / 64; ++it) {
        int t = it * 64 + tid;
        int m = mask[b * SDN + t];
        unsigned long long bal = __ballot(m != 0);
        int pos = run + __popcll(bal & ((1ull << tid) - 1ull));
        if (m) perm_lds[pos] = t;
        run += (int)__popcll(bal);
      }
      int pad = (run + 127) & ~127;        // 128-row quantization (r7 chunks)
      for (int j = run + tid; j < pad; j += 64) perm_lds[j] = -1;
      if (tid == 0) {
        pad_s = pad;
        if (sub == 0) nchunks[bs] = pad >> 7;
      }
    }
    __syncthreads();
    const int pad = pad_s;
    const int l32 = tid & 31;
    #pragma unroll
    for (int p = 0; p < 4; ++p) {          // 8 rows/pass x 32 lanes/row
      int j = sub * 32 + p * 8 + (tid >> 5);
      if (j < pad) {
        int src_t = perm_lds[j];
        float4 v = make_float4(0.f, 0.f, 0.f, 0.f);
        if (src_t >= 0)
          v = ((const float4*)(srcmat + ((size_t)b * SDN + src_t) * HH))[l32];
        short4 o; o.x = f2bf(v.x); o.y = f2bf(v.y); o.z = f2bf(v.z); o.w = f2bf(v.w);
        *(short4*)&od[((size_t)bs * SDN + j) * HH + l32 * 4] = o;
      }
    }
  } else {
    if (blockIdx.x == 2048 && tid == 0) counter[0] = 0;
    const int bq = blockIdx.x - 2048;      // 0..31; q has 131072 float4
    #pragma unroll
    for (int it = 0; it < 16; ++it) {
      int i = bq * 4096 + it * 256 + tid;
      float4 v = ((const float4*)q)[i];
      short4 o; o.x = f2bf(v.x); o.y = f2bf(v.y); o.z = f2bf(v.z); o.w = f2bf(v.w);
      *(short4*)&oq[i * 4] = o;
    }
  }
}

// Persistent maxsim + fused loss. This is round 7's maxsim VERBATIM (the
// empirical best: only round where maxsim dropped under the 45us harness
// fill in the profile; VGPR=104 = fragments actually resident) plus the
// r9 fused-loss epilogue. r8/r10 lesson: the compiler will NOT hold large
// explicit register arrays across iterations (2-query qfrag and global->reg
// ping-pong both got rematerialized/sunk) — the LDS double-buffer with
// 1 query/wave is the only shape where residency + staging both work.
//
// Grid 512 = (16 a-slices x 32 bs-quads), 2 blocks/CU, one dispatch round.
// Block streams 4 bs values flat through a double-buffered 128-row LDS
// pipeline; prefetch of chunk i+1 is ISSUED before compute of chunk i.
// MFMA order: mfma(dfrag, qfrag) -> C[m=t][n=s]; max-over-t is an
// in-register 16-reg v_max tree; per-bs finalize is 9 shuffles.
// d_lds per buffer: 128 rows x 128 bf16, 16B chunks XOR-swizzled
// (chunk c of row r at c^(r&15)): staging + ds_read_b128 conflict-free
// (SQ_LDS_BANK_CONFLICT=0 since round 2).
// launch_bounds(256,2): cap 256 >> ~136 needed -> cannot spill (r3/r4:
// caps below need spilled 843/217 MB scratch).
__global__ __launch_bounds__(256, 2)
void maxsim_kernel(const short* __restrict__ qb,
                   const short* __restrict__ dc,
                   const int* __restrict__ nchunks,
                   float* __restrict__ scores,
                   int* __restrict__ counter,
                   float* __restrict__ out) {
  const int aslc = blockIdx.x;   // 0..15
  const int bs0  = blockIdx.y * 4;

  __shared__ __align__(16) short d_lds[2][128 * 128];  // 2 x 32 KB
  __shared__ int islast_s;
  __shared__ float part[4];

  const int tid = threadIdx.x;
  const int ln  = tid & 63;
  const int w   = tid >> 6;
  const int l31 = ln & 31;
  const int kh  = ln >> 5;
  const int a   = aslc * 4 + w;  // this wave's query (owns all 64 s)

  int nchv[4];
  #pragma unroll
  for (int i = 0; i < 4; ++i) nchv[i] = nchunks[bs0 + i];  // block-uniform

  // ---- q as B-operand (persistent): n = half*32+l31, k = kc*16 + kh*8 + j ----
  bf16x8 qfrag[2][8];
  #pragma unroll
  for (int half = 0; half < 2; ++half) {
    const short* qrow = qb + ((size_t)a * SQN + half * 32 + l31) * HH + kh * 8;
    #pragma unroll
    for (int kc = 0; kc < 8; ++kc)
      qfrag[half][kc] = *(const bf16x8*)(qrow + kc * 16);
  }

  float rmaxh[2] = {0.f, 0.f};   // masked-zero trick: true max >= 0

  // ---- stage chunk (bs0, 0) into buffer 0 ----
  {
    const short* dsrc = dc + (size_t)bs0 * SDN * HH;
    #pragma unroll
    for (int it = 0; it < 8; ++it) {
      int f = it * 256 + tid;
      int row = f >> 4;
      int c = (f & 15) ^ (row & 15);
      gl_lds16(&dsrc[row * HH + c * 8], &d_lds[0][(it * 256 + w * 64) * 8]);
    }
  }
  __syncthreads();

  int bi = 0, tc = 0, buf = 0;
  for (;;) {
    // next flat chunk (possibly first chunk of next bs)
    int nbi = bi, ntc = tc + 1;
    if (ntc == nchv[bi]) { ntc = 0; nbi = bi + 1; }
    const bool hn = (nbi < 4);

    // ---- issue prefetch BEFORE compute (drain lands after ~2048cyc MFMA) ----
    if (hn) {
      const short* dsrc = dc + ((size_t)(bs0 + nbi) * SDN + ntc * 128) * HH;
      short* dst = &d_lds[buf ^ 1][0];
      #pragma unroll
      for (int it = 0; it < 8; ++it) {
        int f = it * 256 + tid;
        int row = f >> 4;
        int c = (f & 15) ^ (row & 15);
        gl_lds16(&dsrc[row * HH + c * 8], &dst[(it * 256 + w * 64) * 8]);
      }
    }

    // ---- compute: 4 t-tiles x 8 kc x 2 s-halves; C[m=t][n=s] ----
    const short* bufp = &d_lds[buf][0];
    #pragma unroll
    for (int tt = 0; tt < 4; ++tt) {
      int trow = tt * 32 + l31;
      int tm = trow & 15;
      const short* bbase = &bufp[trow * HH];
      f32x16 acc0 = {0,0,0,0,0,0,0,0,0,0,0,0,0,0,0,0};
      f32x16 acc1 = {0,0,0,0,0,0,0,0,0,0,0,0,0,0,0,0};
      #pragma unroll
      for (int kc = 0; kc < 8; ++kc) {
        int c = (kc * 2 + kh) ^ tm;
        bf16x8 dfrag = *(const bf16x8*)&bbase[c * 8];  // A: m = t = trow
        acc0 = __builtin_amdgcn_mfma_f32_32x32x16_bf16(dfrag, qfrag[0][kc], acc0, 0, 0, 0);
        acc1 = __builtin_amdgcn_mfma_f32_32x32x16_bf16(dfrag, qfrag[1][kc], acc1, 0, 0, 0);
      }
      // C: col = l31 = s (within half); 16 regs = this lane's kh-group of t's
      float m0 = acc0[0], m1 = acc1[0];
      #pragma unroll
      for (int r = 1; r < 16; ++r) {
        m0 = fmaxf(m0, acc0[r]);
        m1 = fmaxf(m1, acc1[r]);
      }
      rmaxh[0] = fmaxf(rmaxh[0], m0);
      rmaxh[1] = fmaxf(rmaxh[1], m1);
    }

    // ---- finished bs? finalize: cross-kh max, sum over s, store score ----
    if (ntc == 0) {
      float v0 = fmaxf(rmaxh[0], __shfl_xor(rmaxh[0], 32));  // merge kh t-halves
      float v1 = fmaxf(rmaxh[1], __shfl_xor(rmaxh[1], 32));
      float s = v0 + v1;                 // s = l31 and s = 32+l31
      s += __shfl_xor(s, 1);  s += __shfl_xor(s, 2);  s += __shfl_xor(s, 4);
      s += __shfl_xor(s, 8);  s += __shfl_xor(s, 16);
      if (ln == 0) scores[(size_t)a * (2 * BB) + bs0 + bi] = s;
      rmaxh[0] = 0.f; rmaxh[1] = 0.f;
    }

    __syncthreads();   // waves done with buf before re-stage; drains prefetch
    if (!hn) break;
    bi = nbi; tc = ntc; buf ^= 1;
  }

  // ---- fused loss: 512th block to finish computes it ----
  __syncthreads();                 // all waves' score stores issued+drained
  if (tid == 0) {
    __threadfence();               // release: our scores visible device-wide
    int old = atomicAdd(counter, 1);
    islast_s = (old == 511);
  }
  __syncthreads();
  if (!islast_s) return;
  __threadfence();                 // acquire: see all blocks' scores

  // loss = mean_a [ logsumexp(scores[a,:]) - scores[a,a] ]; 4 waves x 16 rows
  float acc = 0.f;
  for (int i = 0; i < 16; ++i) {
    int r = w * 16 + i;
    float v0 = scores[r * 128 + ln];
    float v1 = scores[r * 128 + 64 + ln];
    float mx = fmaxf(v0, v1);
    #pragma unroll
    for (int off = 32; off >= 1; off >>= 1) mx = fmaxf(mx, __shfl_xor(mx, off));
    float e = __expf(v0 - mx) + __expf(v1 - mx);
    #pragma unroll
    for (int off = 32; off >= 1; off >>= 1) e += __shfl_xor(e, off);
    float lse = mx + __logf(e);
    float diag = __shfl(v0, r);    // r < 64: diagonal lives in v0 at lane r
    acc += lse - diag;
  }
  if (ln == 0) part[w] = acc;
  __syncthreads();
  if (tid == 0)
    out[0] = (part[0] + part[1] + part[2] + part[3]) * (1.0f / 64.0f);
}

extern "C" void kernel_launch(void* const* d_in, const int* in_sizes, int n_in,
                              void* d_out, int out_size, void* d_ws, size_t ws_size,
                              hipStream_t stream) {
  const float* q        = (const float*)d_in[0];
  const float* d_pos    = (const float*)d_in[1];
  const float* d_neg    = (const float*)d_in[2];
  const int*   mask_pos = (const int*)d_in[3];
  const int*   mask_neg = (const int*)d_in[4];

  // ws layout: q_bf 1 MB | d_c 16 MB | nchunks | scores | counter
  short* q_bf = (short*)d_ws;                                  // 524288 shorts
  short* d_c  = q_bf + (size_t)BB * SQN * HH;                  // 8388608 shorts
  int*   nchunks = (int*)(d_c + (size_t)2 * BB * SDN * HH);    // 128 ints
  float* scores  = (float*)(nchunks + 128);                    // 8192 floats
  int*   counter = (int*)(scores + BB * 2 * BB);               // 1 int

  convert_kernel<<<2080, 256, 0, stream>>>(q, d_pos, d_neg, mask_pos, mask_neg,
                                           q_bf, d_c, nchunks, counter);

  dim3 grid(16 /*a-slices*/, 32 /*bs-quads*/);
  maxsim_kernel<<<grid, 256, 0, stream>>>(q_bf, d_c, nchunks, scores,
                                          counter, (float*)d_out);
}

// Round 12
// 143.230 us; speedup vs baseline: 1.2421x; 1.0249x over previous
//
#include <hip/hip_runtime.h>
#include <hip/hip_bf16.h>
#include <math.h>
#include <stdint.h>

// Problem: B=64, SQ=64, SD=512, H=128
#define BB 64
#define SQN 64
#define SDN 512
#define HH 128

typedef __attribute__((ext_vector_type(8))) short bf16x8;     // 8 bf16 = 4 VGPRs
typedef __attribute__((ext_vector_type(16))) float f32x16;    // 16 acc regs

__device__ __forceinline__ short f2bf(float f) {
  union { float f; unsigned u; } x; x.f = f;
  unsigned r = x.u + 0x7fffu + ((x.u >> 16) & 1u);   // RNE
  return (short)(r >> 16);
}

__device__ __forceinline__ void gl_lds16(const short* g, short* l) {
  __builtin_amdgcn_global_load_lds(
      (const __attribute__((address_space(1))) unsigned int*)g,
      (__attribute__((address_space(3))) unsigned int*)l, 16, 0, 0);
}

// ---- fused compact+convert (128-row quantization, matches maxsim chunks) ----
// blocks [0,2048): d-gather; each owns 32 compacted rows of one (b,side) and
// redundantly ballot-scans that bs's 512-entry mask in LDS (L2-hit, cheap).
// blocks [2048,2080): q convert; block 2048 zeroes the loss counter.
// Dropping masked rows is exact under the masked-zero argument (maxsim inits
// rmax at 0; true max over ~256 valid t is >= 0 w.p. 1-2^-256). Pad rows
// (perm=-1) convert to zero rows -> dots 0 <= max.
__global__ __launch_bounds__(256)
void convert_kernel(const float* __restrict__ q, const float* __restrict__ dp,
                    const float* __restrict__ dn,
                    const int* __restrict__ mp, const int* __restrict__ mn,
                    short* __restrict__ oq, short* __restrict__ od,
                    int* __restrict__ nchunks, int* __restrict__ counter) {
  const int tid = threadIdx.x;
  if (blockIdx.x < 2048) {
    const int gid = blockIdx.x;
    const int bs  = gid >> 4;       // side*64+b
    const int sub = gid & 15;       // which 32-row slice
    const int side = bs >> 6, b = bs & 63;
    const int* mask = side ? mn : mp;
    const float* srcmat = side ? dn : dp;
    __shared__ int perm_lds[SDN];
    __shared__ int pad_s;
    if (tid < 64) {
      int run = 0;
      #pragma unroll
      for (int it = 0; it < SDN / 64; ++it) {
        int t = it * 64 + tid;
        int m = mask[b * SDN + t];
        unsigned long long bal = __ballot(m != 0);
        int pos = run + __popcll(bal & ((1ull << tid) - 1ull));
        if (m) perm_lds[pos] = t;
        run += (int)__popcll(bal);
      }
      int pad = (run + 127) & ~127;        // 128-row quantization
      for (int j = run + tid; j < pad; j += 64) perm_lds[j] = -1;
      if (tid == 0) {
        pad_s = pad;
        if (sub == 0) nchunks[bs] = pad >> 7;
      }
    }
    __syncthreads();
    const int pad = pad_s;
    const int l32 = tid & 31;
    #pragma unroll
    for (int p = 0; p < 4; ++p) {          // 8 rows/pass x 32 lanes/row
      int j = sub * 32 + p * 8 + (tid >> 5);
      if (j < pad) {
        int src_t = perm_lds[j];
        float4 v = make_float4(0.f, 0.f, 0.f, 0.f);
        if (src_t >= 0)
          v = ((const float4*)(srcmat + ((size_t)b * SDN + src_t) * HH))[l32];
        short4 o; o.x = f2bf(v.x); o.y = f2bf(v.y); o.z = f2bf(v.z); o.w = f2bf(v.w);
        *(short4*)&od[((size_t)bs * SDN + j) * HH + l32 * 4] = o;
      }
    }
  } else {
    if (blockIdx.x == 2048 && tid == 0) counter[0] = 0;
    const int bq = blockIdx.x - 2048;      // 0..31; q has 131072 float4
    #pragma unroll
    for (int it = 0; it < 16; ++it) {
      int i = bq * 4096 + it * 256 + tid;
      float4 v = ((const float4*)q)[i];
      short4 o; o.x = f2bf(v.x); o.y = f2bf(v.y); o.z = f2bf(v.z); o.w = f2bf(v.w);
      *(short4*)&oq[i * 4] = o;
    }
  }
}

// Persistent maxsim + fused loss, XCD-SWIZZLED.
//
// Round 11 finding: every structural variant (r8-r11) pins at 64-65 us =
// staged bytes (~200 MB) / ~2.6 TB/s -> the kernel is staging-BW-bound.
// Root cause: the 16 a-slice blocks sharing a bs-quad round-robin across
// all 8 XCDs, so each 4 MiB XCD-L2 re-pulls ~all of d_c (16.7 MB) from LLC.
//
// Fix: 1-D grid of 512, decode xcd = blockIdx%8 (dispatch round-robin
// heuristic, perf-only) and co-locate ALL 16 a-slice blocks of a bs-quad on
// one XCD. Each XCD then owns 4 bs-quads: 1.3 MB d + 1 MB q, L2-resident.
// Chunks are pulled from LLC once and re-served 15x at XCD-L2 BW; the 32 KB
// drain (~600 cyc) hides inside the 2048-cyc MFMA shadow.
//
// Everything else identical to r11 (the proven-resident shape: VGPR=124,
// 1 query/wave, 128-row LDS dbuf, prefetch-before-compute, in-register max
// tree, 9-shuffle finalize, fused last-block loss).
// launch_bounds(256,2): cap 256 >> need -> cannot spill (r3/r4 lesson).
__global__ __launch_bounds__(256, 2)
void maxsim_kernel(const short* __restrict__ qb,
                   const short* __restrict__ dc,
                   const int* __restrict__ nchunks,
                   float* __restrict__ scores,
                   int* __restrict__ counter,
                   float* __restrict__ out) {
  // ---- XCD-aware decode: all 16 aslc blocks of a bs-quad on one XCD ----
  const int j    = blockIdx.x;        // 0..511
  const int xcd  = j & 7;             // dispatch round-robin heuristic
  const int slot = j >> 3;            // 0..63 within XCD
  const int bsq  = xcd * 4 + (slot >> 4);   // 0..31: 4 bs-quads per XCD
  const int aslc = slot & 15;               // 0..15
  const int bs0  = bsq * 4;

  __shared__ __align__(16) short d_lds[2][128 * 128];  // 2 x 32 KB
  __shared__ int islast_s;
  __shared__ float part[4];

  const int tid = threadIdx.x;
  const int ln  = tid & 63;
  const int w   = tid >> 6;
  const int l31 = ln & 31;
  const int kh  = ln >> 5;
  const int a   = aslc * 4 + w;  // this wave's query (owns all 64 s)

  int nchv[4];
  #pragma unroll
  for (int i = 0; i < 4; ++i) nchv[i] = nchunks[bs0 + i];  // block-uniform

  // ---- q as B-operand (persistent): n = half*32+l31, k = kc*16 + kh*8 + j ----
  bf16x8 qfrag[2][8];
  #pragma unroll
  for (int half = 0; half < 2; ++half) {
    const short* qrow = qb + ((size_t)a * SQN + half * 32 + l31) * HH + kh * 8;
    #pragma unroll
    for (int kc = 0; kc < 8; ++kc)
      qfrag[half][kc] = *(const bf16x8*)(qrow + kc * 16);
  }

  float rmaxh[2] = {0.f, 0.f};   // masked-zero trick: true max >= 0

  // ---- stage chunk (bs0, 0) into buffer 0 ----
  {
    const short* dsrc = dc + (size_t)bs0 * SDN * HH;
    #pragma unroll
    for (int it = 0; it < 8; ++it) {
      int f = it * 256 + tid;
      int row = f >> 4;
      int c = (f & 15) ^ (row & 15);
      gl_lds16(&dsrc[row * HH + c * 8], &d_lds[0][(it * 256 + w * 64) * 8]);
    }
  }
  __syncthreads();

  int bi = 0, tc = 0, buf = 0;
  for (;;) {
    // next flat chunk (possibly first chunk of next bs)
    int nbi = bi, ntc = tc + 1;
    if (ntc == nchv[bi]) { ntc = 0; nbi = bi + 1; }
    const bool hn = (nbi < 4);

    // ---- issue prefetch BEFORE compute (drain lands after ~2048cyc MFMA) ----
    if (hn) {
      const short* dsrc = dc + ((size_t)(bs0 + nbi) * SDN + ntc * 128) * HH;
      short* dst = &d_lds[buf ^ 1][0];
      #pragma unroll
      for (int it = 0; it < 8; ++it) {
        int f = it * 256 + tid;
        int row = f >> 4;
        int c = (f & 15) ^ (row & 15);
        gl_lds16(&dsrc[row * HH + c * 8], &dst[(it * 256 + w * 64) * 8]);
      }
    }

    // ---- compute: 4 t-tiles x 8 kc x 2 s-halves; C[m=t][n=s] ----
    const short* bufp = &d_lds[buf][0];
    #pragma unroll
    for (int tt = 0; tt < 4; ++tt) {
      int trow = tt * 32 + l31;
      int tm = trow & 15;
      const short* bbase = &bufp[trow * HH];
      f32x16 acc0 = {0,0,0,0,0,0,0,0,0,0,0,0,0,0,0,0};
      f32x16 acc1 = {0,0,0,0,0,0,0,0,0,0,0,0,0,0,0,0};
      #pragma unroll
      for (int kc = 0; kc < 8; ++kc) {
        int c = (kc * 2 + kh) ^ tm;
        bf16x8 dfrag = *(const bf16x8*)&bbase[c * 8];  // A: m = t = trow
        acc0 = __builtin_amdgcn_mfma_f32_32x32x16_bf16(dfrag, qfrag[0][kc], acc0, 0, 0, 0);
        acc1 = __builtin_amdgcn_mfma_f32_32x32x16_bf16(dfrag, qfrag[1][kc], acc1, 0, 0, 0);
      }
      // C: col = l31 = s (within half); 16 regs = this lane's kh-group of t's
      float m0 = acc0[0], m1 = acc1[0];
      #pragma unroll
      for (int r = 1; r < 16; ++r) {
        m0 = fmaxf(m0, acc0[r]);
        m1 = fmaxf(m1, acc1[r]);
      }
      rmaxh[0] = fmaxf(rmaxh[0], m0);
      rmaxh[1] = fmaxf(rmaxh[1], m1);
    }

    // ---- finished bs? finalize: cross-kh max, sum over s, store score ----
    if (ntc == 0) {
      float v0 = fmaxf(rmaxh[0], __shfl_xor(rmaxh[0], 32));  // merge kh t-halves
      float v1 = fmaxf(rmaxh[1], __shfl_xor(rmaxh[1], 32));
      float s = v0 + v1;                 // s = l31 and s = 32+l31
      s += __shfl_xor(s, 1);  s += __shfl_xor(s, 2);  s += __shfl_xor(s, 4);
      s += __shfl_xor(s, 8);  s += __shfl_xor(s, 16);
      if (ln == 0) scores[(size_t)a * (2 * BB) + bs0 + bi] = s;
      rmaxh[0] = 0.f; rmaxh[1] = 0.f;
    }

    __syncthreads();   // waves done with buf before re-stage; drains prefetch
    if (!hn) break;
    bi = nbi; tc = ntc; buf ^= 1;
  }

  // ---- fused loss: 512th block to finish computes it ----
  __syncthreads();                 // all waves' score stores issued+drained
  if (tid == 0) {
    __threadfence();               // release: our scores visible device-wide
    int old = atomicAdd(counter, 1);
    islast_s = (old == 511);
  }
  __syncthreads();
  if (!islast_s) return;
  __threadfence();                 // acquire: see all blocks' scores

  // loss = mean_a [ logsumexp(scores[a,:]) - scores[a,a] ]; 4 waves x 16 rows
  float acc = 0.f;
  for (int i = 0; i < 16; ++i) {
    int r = w * 16 + i;
    float v0 = scores[r * 128 + ln];
    float v1 = scores[r * 128 + 64 + ln];
    float mx = fmaxf(v0, v1);
    #pragma unroll
    for (int off = 32; off >= 1; off >>= 1) mx = fmaxf(mx, __shfl_xor(mx, off));
    float e = __expf(v0 - mx) + __expf(v1 - mx);
    #pragma unroll
    for (int off = 32; off >= 1; off >>= 1) e += __shfl_xor(e, off);
    float lse = mx + __logf(e);
    float diag = __shfl(v0, r);    // r < 64: diagonal lives in v0 at lane r
    acc += lse - diag;
  }
  if (ln == 0) part[w] = acc;
  __syncthreads();
  if (tid == 0)
    out[0] = (part[0] + part[1] + part[2] + part[3]) * (1.0f / 64.0f);
}

extern "C" void kernel_launch(void* const* d_in, const int* in_sizes, int n_in,
                              void* d_out, int out_size, void* d_ws, size_t ws_size,
                              hipStream_t stream) {
  const float* q        = (const float*)d_in[0];
  const float* d_pos    = (const float*)d_in[1];
  const float* d_neg    = (const float*)d_in[2];
  const int*   mask_pos = (const int*)d_in[3];
  const int*   mask_neg = (const int*)d_in[4];

  // ws layout: q_bf 1 MB | d_c 16 MB | nchunks | scores | counter
  short* q_bf = (short*)d_ws;                                  // 524288 shorts
  short* d_c  = q_bf + (size_t)BB * SQN * HH;                  // 8388608 shorts
  int*   nchunks = (int*)(d_c + (size_t)2 * BB * SDN * HH);    // 128 ints
  float* scores  = (float*)(nchunks + 128);                    // 8192 floats
  int*   counter = (int*)(scores + BB * 2 * BB);               // 1 int

  convert_kernel<<<2080, 256, 0, stream>>>(q, d_pos, d_neg, mask_pos, mask_neg,
                                           q_bf, d_c, nchunks, counter);

  maxsim_kernel<<<512, 256, 0, stream>>>(q_bf, d_c, nchunks, scores,
                                         counter, (float*)d_out);
}